// Round 5
// baseline (26415.915 us; speedup 1.0000x reference)
//
#include <hip/hip_runtime.h>
#include <hip/hip_bf16.h>

// LSTM B=256 T=512 H=256 E=6 V=10 C=10. fp32 in/out.
// ROUND 20: M-SPLIT across block pairs to break the per-block MFMA floor.
// r18's interval = 1307cy MFMA-pipe floor (64 MFMAs/SIMD, invariant within
// one block) + ~460 last-wave elem + ~620 overhead = 2390cy. r16/r19 proved
// intra-block desync can't win (all-to-all dep + symmetric waves -> lockstep
// attractor; flag cost pure overhead). This round: colpair j handled by TWO
// blocks (j, j+128); side s owns 128 output rows -> 32 MFMAs/SIMD/step
// (653cy floor). Own-half h via LDS (double-buffered); partner's 128 h-rows
// (256B/step) exchanged via global ws slots (parity ping-pong) + monotonic
// per-(pair,side) flag counters, release/acquire at agent scope. Flag poll
// issued RELAXED at interval start (hides L2 latency under own-K MFMAs),
// acquire-fence before partner loads (also invalidates L1 - required, else
// stale hits). ABA across launches killed by hipMemsetAsync(ws) in
// kernel_launch (graph-capture legal). 256 blocks <= 256 CUs x 1-block
// capacity -> co-residency guaranteed, no deadlock. i32 MFMA accumulation
// associative -> bit-identical to r18 (absmax must stay 0.0078125). Final
// h published as exact bf16 for the projection. Fallback kernel (r18
// verbatim) if ws_size too small.
// Kept from r18: INT8 MFMA 16x16x64, reg-resident per-row-quantized weights
// (wa[4][4]=64 VGPR now), h @127 LDS, x-path table (now col-independent RAW
// tblS 40KB + per-col bias regs; tb = (s+b)*K same fp ops as r18 -> bit
// identical), Z C-operand, per-gate elem tails, single-rcp c-update,
// constant-index cndmask select.

typedef __attribute__((ext_vector_type(4))) int   int4v;
typedef __attribute__((ext_vector_type(4))) float float4v;

#define MFMA_I8(a, b, c) __builtin_amdgcn_mfma_i32_16x16x64_i8(a, b, c, 0, 0, 0)

#define K_TANH (-2.8853900817779268f)   // exp2(K_TANH*x) = e^(-2x)
#define K_SIG  (-1.4426950408889634f)   // exp2(K_SIG*x)  = e^(-x)

// ---- workspace layout ----
#define WS_FL   0                        // int fl[128][2] (+pad)
#define WS_HX   4096                     // i8 hx[2][128][2][2][128] = 131072
#define WS_HFG  (4096 + 131072)          // short hfg[128][2][2][128] = 131072
#define WS_NEED (4096 + 131072 + 131072)

__device__ __forceinline__ short f2b(float f) {
    __hip_bfloat16 b = __float2bfloat16(f); return *(short*)&b;
}
__device__ __forceinline__ float b2f(short s) {
    union { unsigned int u; float f; } v; v.u = ((unsigned int)(unsigned short)s) << 16; return v.f;
}
__device__ __forceinline__ float fexp2(float x) {
#if __has_builtin(__builtin_amdgcn_exp2f)
    return __builtin_amdgcn_exp2f(x);
#else
    return __expf(x * 0.6931471805599453f);
#endif
}
__device__ __forceinline__ float frcp(float x) { return __builtin_amdgcn_rcpf(x); }

// ============================ M-split kernel ============================
__global__ __attribute__((amdgpu_flat_work_group_size(512, 512), amdgpu_waves_per_eu(2, 2)))
void lstm_i8_split(
    const int* __restrict__ x,
    const float* __restrict__ emb,
    const float* __restrict__ Wxg, const float* __restrict__ Whg, const float* __restrict__ bg,
    const float* __restrict__ Wxi, const float* __restrict__ Whi, const float* __restrict__ bi,
    const float* __restrict__ Wxf, const float* __restrict__ Whf, const float* __restrict__ bff,
    const float* __restrict__ Wxo, const float* __restrict__ Who, const float* __restrict__ bo,
    const float* __restrict__ Wp, const float* __restrict__ bp,
    char* __restrict__ ws,
    float* __restrict__ out)
{
    const int tid = threadIdx.x, bid = blockIdx.x;
    const int j = bid & 127;                // colpair id
    const int s = bid >> 7;                 // side: rows [128s, 128s+128)
    const int c0 = j * 2;
    const int w = tid >> 6, lane = tid & 63;
    const int l = lane & 15, q = lane >> 4;
    const int col = lane & 1;               // batch-col parity
    const int si  = (lane >> 1) & 3;        // acc reg select
    const int dup = (lane >> 3) & 1;        // 2x duplicate bit
    const int rloc  = 16 * w + 4 * q + si;  // own-local row 0..127
    const int rglob = 128 * s + rloc;       // global hidden row

    __shared__ __align__(16) char hbuf[2][2 * 160];   // [parity][col*160 + klocal]
    __shared__ __align__(16) short hfin[2 * 264];     // final h bf16 [col][k]
    __shared__ unsigned char xdig2[512 * 2];          // [t][col]
    __shared__ __align__(16) float tblS[10 * 1024];   // [d][r][4g] RAW x-path (no bias/K)
    __shared__ float scaleL[4 * 256];                 // per-gate per-row max|W|

    const float* WxT[4] = {Wxg, Wxi, Wxf, Wxo};
    const float* WhT[4] = {Whg, Whi, Whf, Who};
    const float* bT[4]  = {bg, bi, bff, bo};

    // ---- ws pointers ----
    int*   flB  = (int*)(ws + WS_FL);
    int*   flagMe = flB + (j * 2 + s);
    int*   flagP  = flB + (j * 2 + (1 - s));
    char*  hxB  = ws + WS_HX;                 // [(p*128+j)*2+side]*256 + col*128 + k
    short* hfgB = (short*)(ws + WS_HFG);      // [(j*2+side)*256 + col*128 + k]

    // ---- init: digits + raw x-path table ----
    for (int i = tid; i < 1024; i += 512)
        xdig2[i] = (unsigned char)x[(c0 + (i & 1)) * 512 + (i >> 1)];

    for (int i = tid; i < 2560; i += 512) {
        int d = i >> 8, r = i & 255;
        float4v v;
        #pragma unroll
        for (int g = 0; g < 4; g++) {
            float sx = 0.f;
            #pragma unroll
            for (int e = 0; e < 6; e++) sx += WxT[g][r * 6 + e] * emb[d * 6 + e];
            v[g] = sx;                         // RAW: bias+K applied per-elem
        }
        *(float4v*)&tblS[d * 1024 + r * 4] = v;
    }

    // ---- weight quantization: per-row scale over FULL k, frags in
    //      consumption order: own kts {2s,2s+1} then partner {2-2s,3-2s} ----
    int4v wa[4][4];
    int karr[4] = {2 * s, 2 * s + 1, 2 - 2 * s, 3 - 2 * s};
    #pragma unroll
    for (int g = 0; g < 4; g++) {
        const float* Wr = WhT[g] + (128 * s + 16 * w + l) * 256 + q * 16;
        float mx = 0.f;
        #pragma unroll
        for (int kt = 0; kt < 4; kt++)
            #pragma unroll
            for (int c4 = 0; c4 < 4; c4++) {
                float4v v = *(const float4v*)(Wr + kt * 64 + c4 * 4);
                #pragma unroll
                for (int jj = 0; jj < 4; jj++) mx = fmaxf(mx, fabsf(v[jj]));
            }
        mx = fmaxf(mx, __shfl_xor(mx, 16));
        mx = fmaxf(mx, __shfl_xor(mx, 32));
        mx = fmaxf(mx, 1e-20f);
        if (q == 0) scaleL[g * 256 + 128 * s + 16 * w + l] = mx;
        float qs = 127.f / mx;
        #pragma unroll
        for (int c = 0; c < 4; c++) {
            const float* Wc = Wr + karr[c] * 64;   // runtime in ADDRESS only
            int4v f;
            #pragma unroll
            for (int dw = 0; dw < 4; dw++) {
                float4v v = *(const float4v*)(Wc + dw * 4);
                int word = 0;
                #pragma unroll
                for (int byt = 0; byt < 4; byt++) {
                    int z = (int)rintf(v[byt] * qs);
                    word |= (z & 255) << (8 * byt);
                }
                f[dw] = word;
            }
            wa[g][c] = f;
        }
    }

    __syncthreads();   // tblS/scaleL/xdig2 visible

    // ---- loop-invariants ----
    float dscl[4], brv[4];
    #pragma unroll
    for (int g = 0; g < 4; g++) {
        float kk = (g == 0 ? K_TANH : K_SIG) * (1.f / 16129.f);   // 127^2
        dscl[g] = scaleL[g * 256 + rglob] * kk;
        brv[g]  = bT[g][c0 + col];
    }
    const bool bi1 = (si & 1) != 0;
    const bool bi2 = (si & 2) != 0;
    const float* tprow = tblS + rglob * 4;      // + d*1024 at runtime
    const int lOff0 = col * 160 + 0  + q * 16;  // own-k LDS frag offsets
    const int lOff1 = col * 160 + 64 + q * 16;
    const int pOff0 = col * 128 + 0  + q * 16;  // partner-k global frag offsets
    const int pOff1 = col * 128 + 64 + q * 16;
    const int hoffL = col * 160 + rloc;         // own h byte in LDS
    const int hoffG = col * 128 + rloc;         // own h byte in global slot
    const int4v Z = {0, 0, 0, 0};

    float cs, hl;

    // ---- t=0 prologue: h(0)=0 -> av=0 exactly (matches r18's zero-h MFMA) ----
    {
        int dg = xdig2[0 * 2 + col];
        float4v ts0 = *(const float4v*)(tprow + dg * 1024);
        float tb0 = (ts0[0] + brv[0]) * K_TANH;
        float tb1 = (ts0[1] + brv[1]) * K_SIG;
        float tb2 = (ts0[2] + brv[2]) * K_SIG;
        float tb3 = (ts0[3] + brv[3]) * K_SIG;
        float Eg = fexp2(tb0), Ei = fexp2(tb1), Ef = fexp2(tb2), Eo = fexp2(tb3);
        float m1  = (1.f + Eg) * (1.f + Ei);
        float fp1 = 1.f + Ef;
        float num = (1.f - Eg) * fp1;            // fmaf(0, m1, x) == x exactly
        float c   = num * frcp(m1 * fp1);
        cs = c;
        float Ec = fexp2(K_TANH * c);
        hl = (1.f - Ec) * frcp((1.f + Ec) * (1.f + Eo));
        if (!dup) {
            char hq = (char)((int)rintf(hl * 127.f));
            hbuf[1][hoffL] = hq;                                  // h(1), parity 1
            *(hxB + ((1 * 128 + j) * 2 + s) * 256 + hoffG) = hq;  // publish h(1)
        }
    }
    __threadfence();
    __syncthreads();
    if (tid == 0)
        __hip_atomic_store(flagMe, 1, __ATOMIC_RELEASE, __HIP_MEMORY_SCOPE_AGENT);

    // prefetch raw x-path for t=1
    float4v ts;
    { int dg = xdig2[1 * 2 + col]; ts = *(const float4v*)(tprow + dg * 1024); }

    int fpre = 0;

    for (int t = 1; t < 512; ++t) {
        const int p = t & 1;

        // early relaxed flag probe (L2 latency hides under own-K MFMAs)
        int fnow = __hip_atomic_load(flagP, __ATOMIC_RELAXED, __HIP_MEMORY_SCOPE_AGENT);

        const char* hb = hbuf[p];
        int4v ho0 = *(const int4v*)(hb + lOff0);
        int4v ho1 = *(const int4v*)(hb + lOff1);

        // own-K MFMAs (8): 4 gates x 2 own k-tiles, round-robin chains
        int4v ag = MFMA_I8(wa[0][0], ho0, Z);
        int4v ai = MFMA_I8(wa[1][0], ho0, Z);
        int4v af = MFMA_I8(wa[2][0], ho0, Z);
        int4v ao = MFMA_I8(wa[3][0], ho0, Z);
        ag = MFMA_I8(wa[0][1], ho1, ag);
        ai = MFMA_I8(wa[1][1], ho1, ai);
        af = MFMA_I8(wa[2][1], ho1, af);
        ao = MFMA_I8(wa[3][1], ho1, ao);

        // partner handshake: need flag >= t (monotonic; cached pass is safe)
        if (fnow > fpre) fpre = fnow;
        if (fpre < t) {
            int cap = 0, v;
            do { v = __hip_atomic_load(flagP, __ATOMIC_RELAXED, __HIP_MEMORY_SCOPE_AGENT); }
            while (v < t && ++cap < (1 << 27));
            fpre = v;
        }
        __builtin_amdgcn_fence(__ATOMIC_ACQUIRE, "agent");   // order + L1 inv

        const char* hp = hxB + ((p * 128 + j) * 2 + (1 - s)) * 256;
        int4v hp0 = *(const int4v*)(hp + pOff0);
        int4v hp1 = *(const int4v*)(hp + pOff1);

        ag = MFMA_I8(wa[0][2], hp0, ag);
        ai = MFMA_I8(wa[1][2], hp0, ai);
        af = MFMA_I8(wa[2][2], hp0, af);
        ao = MFMA_I8(wa[3][2], hp0, ao);

        // prefetch raw x-path for t+1 (independent of h)
        float4v tsn;
        { int dgn = xdig2[((t + 1) & 511) * 2 + col]; tsn = *(const float4v*)(tprow + dgn * 1024); }

        // per-gate final MFMA + that gate's elem chunk (r18 tail structure)
        ag = MFMA_I8(wa[0][3], hp1, ag);
        int avg_;
        { int s0 = bi1 ? ag[1] : ag[0]; int s1 = bi1 ? ag[3] : ag[2]; avg_ = bi2 ? s1 : s0; }
        float tbg = (ts[0] + brv[0]) * K_TANH;
        float pg = fmaf((float)avg_, dscl[0], tbg);
        float Eg = fexp2(pg);

        ai = MFMA_I8(wa[1][3], hp1, ai);
        int avi_;
        { int s0 = bi1 ? ai[1] : ai[0]; int s1 = bi1 ? ai[3] : ai[2]; avi_ = bi2 ? s1 : s0; }
        float tbi = (ts[1] + brv[1]) * K_SIG;
        float pi = fmaf((float)avi_, dscl[1], tbi);
        float Ei = fexp2(pi);
        float m1 = (1.f + Eg) * (1.f + Ei);

        af = MFMA_I8(wa[2][3], hp1, af);
        int avf_;
        { int s0 = bi1 ? af[1] : af[0]; int s1 = bi1 ? af[3] : af[2]; avf_ = bi2 ? s1 : s0; }
        float tbf = (ts[2] + brv[2]) * K_SIG;
        float pf = fmaf((float)avf_, dscl[2], tbf);
        float Ef = fexp2(pf);
        // c = [(1-Eg)(1+Ef) + cs(1+Eg)(1+Ei)] / [(1+Eg)(1+Ei)(1+Ef)]  (one rcp)
        float fp1 = 1.f + Ef;
        float num = fmaf(cs, m1, (1.f - Eg) * fp1);
        float c   = num * frcp(m1 * fp1);
        cs = c;
        float Ec = fexp2(K_TANH * c);

        ao = MFMA_I8(wa[3][3], hp1, ao);
        int avo_;
        { int s0 = bi1 ? ao[1] : ao[0]; int s1 = bi1 ? ao[3] : ao[2]; avo_ = bi2 ? s1 : s0; }
        float tbo = (ts[3] + brv[3]) * K_SIG;
        float po = fmaf((float)avo_, dscl[3], tbo);
        float Eo = fexp2(po);
        float hh = (1.f - Ec) * frcp((1.f + Ec) * (1.f + Eo));   // tanh(c)*sig(o)
        hl = hh;

        if (!dup) {
            char hq = (char)((int)rintf(hh * 127.f));
            hbuf[1 - p][hoffL] = hq;                 // own h(t+1) for own-K
            if (t < 511) {
                *(hxB + (((1 - p) * 128 + j) * 2 + s) * 256 + hoffG) = hq;
            } else {
                hfgB[(j * 2 + s) * 256 + hoffG] = f2b(hl);   // exact bf16 final
            }
        }
        __threadfence();       // own global stores visible before flag bump
        __syncthreads();       // own LDS h(t+1) complete for next interval
        if (tid == 0)
            __hip_atomic_store(flagMe, t + 1, __ATOMIC_RELEASE, __HIP_MEMORY_SCOPE_AGENT);
        ts = tsn;
    }

    // ---- final handshake: partner's exact-bf16 h ----
    {
        int cap = 0, v;
        do { v = __hip_atomic_load(flagP, __ATOMIC_ACQUIRE, __HIP_MEMORY_SCOPE_AGENT); }
        while (v < 512 && ++cap < (1 << 27));
    }
    if (!dup) hfin[col * 264 + rglob] = f2b(hl);
    if (tid < 256) {
        int cc = tid >> 7, k = tid & 127;
        hfin[cc * 264 + 128 * (1 - s) + k] = hfgB[(j * 2 + (1 - s)) * 256 + cc * 128 + k];
    }
    __syncthreads();

    // ---- projection (side 0 only; both sides have identical hfin) ----
    if (s == 0 && tid < 20) {
        int pc = tid / 10, cls = tid - pc * 10;
        const short* hcol = &hfin[pc * 264];
        const float* wrow = Wp + cls * 256;
        float sm = 0.f;
        #pragma unroll 8
        for (int k = 0; k < 256; k++) sm += b2f(hcol[k]) * wrow[k];
        out[(c0 + pc) * 10 + cls] = sm + bp[cls];
    }
}

// ============================ fallback: r18 verbatim ============================
__global__ __attribute__((amdgpu_flat_work_group_size(512, 512), amdgpu_waves_per_eu(2, 2)))
void lstm_i8_fb(
    const int* __restrict__ x,
    const float* __restrict__ emb,
    const float* __restrict__ Wxg, const float* __restrict__ Whg, const float* __restrict__ bg,
    const float* __restrict__ Wxi, const float* __restrict__ Whi, const float* __restrict__ bi,
    const float* __restrict__ Wxf, const float* __restrict__ Whf, const float* __restrict__ bff,
    const float* __restrict__ Wxo, const float* __restrict__ Who, const float* __restrict__ bo,
    const float* __restrict__ Wp, const float* __restrict__ bp,
    float* __restrict__ out)
{
    const int tid = threadIdx.x, bid = blockIdx.x;
    const int c0 = bid * 2;
    const int w = tid >> 6, lane = tid & 63;
    const int l = lane & 15, q = lane >> 4;
    const int col = lane & 1;
    const int rtb = (lane >> 1) & 1;
    const int si  = (lane >> 2) & 3;
    const int rwb = 32 * w;
    const int row = rwb + 16 * rtb + 4 * q + si;

    __shared__ __align__(16) unsigned int hbuf[2][2 * 320 / 4];
    __shared__ __align__(16) short hfin[2 * 264];
    __shared__ unsigned char xdig2[512 * 2];
    __shared__ __align__(16) float tblC[2 * 10 * 1024];
    __shared__ float scaleL[4 * 256];

    const float* WxT[4] = {Wxg, Wxi, Wxf, Wxo};
    const float* WhT[4] = {Whg, Whi, Whf, Who};
    const float* bT[4]  = {bg, bi, bff, bo};

    if (tid < 2 * 320 / 4) hbuf[0][tid] = 0u;
    for (int i = tid; i < 1024; i += 512)
        xdig2[i] = (unsigned char)x[(c0 + (i & 1)) * 512 + (i >> 1)];

    for (int i = tid; i < 5120; i += 512) {
        int cc  = i / 2560;
        int rem = i - cc * 2560;
        int d = rem >> 8, r = rem & 255;
        float4v v;
        #pragma unroll
        for (int g = 0; g < 4; g++) {
            float sx = 0.f;
            #pragma unroll
            for (int e = 0; e < 6; e++) sx += WxT[g][r * 6 + e] * emb[d * 6 + e];
            v[g] = (sx + bT[g][c0 + cc]) * (g == 0 ? K_TANH : K_SIG);
        }
        *(float4v*)&tblC[cc * 10240 + d * 1024 + r * 4] = v;
    }

    int4v wa[2][4][4];
    #pragma unroll
    for (int rt = 0; rt < 2; rt++) {
        #pragma unroll
        for (int g = 0; g < 4; g++) {
            const float* Wr = WhT[g] + (rwb + rt * 16 + l) * 256 + q * 16;
            float mx = 0.f;
            #pragma unroll
            for (int kt = 0; kt < 4; kt++)
                #pragma unroll
                for (int c4 = 0; c4 < 4; c4++) {
                    float4v v = *(const float4v*)(Wr + kt * 64 + c4 * 4);
                    #pragma unroll
                    for (int jj = 0; jj < 4; jj++) mx = fmaxf(mx, fabsf(v[jj]));
                }
            mx = fmaxf(mx, __shfl_xor(mx, 16));
            mx = fmaxf(mx, __shfl_xor(mx, 32));
            mx = fmaxf(mx, 1e-20f);
            if (q == 0) scaleL[g * 256 + rwb + rt * 16 + l] = mx;
            float qs = 127.f / mx;
            #pragma unroll
            for (int kt = 0; kt < 4; kt++) {
                int4v f;
                #pragma unroll
                for (int dw = 0; dw < 4; dw++) {
                    float4v v = *(const float4v*)(Wr + kt * 64 + dw * 4);
                    int word = 0;
                    #pragma unroll
                    for (int byt = 0; byt < 4; byt++) {
                        int z = (int)rintf(v[byt] * qs);
                        word |= (z & 255) << (8 * byt);
                    }
                    f[dw] = word;
                }
                wa[rt][g][kt] = f;
            }
        }
    }

    __syncthreads();

    float dscl[4];
    #pragma unroll
    for (int g = 0; g < 4; g++) {
        float kk = (g == 0 ? K_TANH : K_SIG) * (1.f / 16129.f);
        dscl[g] = scaleL[g * 256 + row] * kk;
    }

    const bool bi1 = (si & 1) != 0;
    const bool bi2 = (si & 2) != 0;
    const bool brt = rtb != 0;
    const float* tprow = tblC + col * 10240 + row * 4;
    const int hoff = col * 320 + row;
    const int4v Z = {0, 0, 0, 0};

    float cs = 0.f, hl = 0.f;

    float4v tb;
    { int dg = xdig2[0 * 2 + col]; tb = *(const float4v*)(tprow + dg * 1024); }

    for (int t = 0; t < 512; t++) {
        const int p = t & 1;
        const char* hbase = (const char*)hbuf[p] + col * 320 + q * 16;

        int4v hf0 = *(const int4v*)(hbase + 0 * 64);
        int4v hf1 = *(const int4v*)(hbase + 1 * 64);
        int4v hf2 = *(const int4v*)(hbase + 2 * 64);
        int4v hf3 = *(const int4v*)(hbase + 3 * 64);

        int4v ag0 = MFMA_I8(wa[0][0][0], hf0, Z);
        int4v ag1 = MFMA_I8(wa[1][0][0], hf0, Z);
        int4v ai0 = MFMA_I8(wa[0][1][0], hf0, Z);
        int4v ai1 = MFMA_I8(wa[1][1][0], hf0, Z);
        int4v af0 = MFMA_I8(wa[0][2][0], hf0, Z);
        int4v af1 = MFMA_I8(wa[1][2][0], hf0, Z);
        int4v ao0 = MFMA_I8(wa[0][3][0], hf0, Z);
        int4v ao1 = MFMA_I8(wa[1][3][0], hf0, Z);
        ag0 = MFMA_I8(wa[0][0][1], hf1, ag0);
        ag1 = MFMA_I8(wa[1][0][1], hf1, ag1);
        ai0 = MFMA_I8(wa[0][1][1], hf1, ai0);
        ai1 = MFMA_I8(wa[1][1][1], hf1, ai1);
        af0 = MFMA_I8(wa[0][2][1], hf1, af0);
        af1 = MFMA_I8(wa[1][2][1], hf1, af1);
        ao0 = MFMA_I8(wa[0][3][1], hf1, ao0);
        ao1 = MFMA_I8(wa[1][3][1], hf1, ao1);
        ag0 = MFMA_I8(wa[0][0][2], hf2, ag0);
        ag1 = MFMA_I8(wa[1][0][2], hf2, ag1);
        ai0 = MFMA_I8(wa[0][1][2], hf2, ai0);
        ai1 = MFMA_I8(wa[1][1][2], hf2, ai1);
        af0 = MFMA_I8(wa[0][2][2], hf2, af0);
        af1 = MFMA_I8(wa[1][2][2], hf2, af1);
        ao0 = MFMA_I8(wa[0][3][2], hf2, ao0);
        ao1 = MFMA_I8(wa[1][3][2], hf2, ao1);

        float4v tbn;
        { int dgn = xdig2[((t + 1) & 511) * 2 + col]; tbn = *(const float4v*)(tprow + dgn * 1024); }

        ag0 = MFMA_I8(wa[0][0][3], hf3, ag0);
        ag1 = MFMA_I8(wa[1][0][3], hf3, ag1);
        int avg_;
        { int t0 = bi1 ? ag0[1] : ag0[0]; int t1 = bi1 ? ag0[3] : ag0[2]; int s0 = bi2 ? t1 : t0;
          int u0 = bi1 ? ag1[1] : ag1[0]; int u1 = bi1 ? ag1[3] : ag1[2]; int s1 = bi2 ? u1 : u0;
          avg_ = brt ? s1 : s0; }
        float pg = fmaf((float)avg_, dscl[0], tb[0]);
        float Eg = fexp2(pg);

        ai0 = MFMA_I8(wa[0][1][3], hf3, ai0);
        ai1 = MFMA_I8(wa[1][1][3], hf3, ai1);
        int avi_;
        { int t0 = bi1 ? ai0[1] : ai0[0]; int t1 = bi1 ? ai0[3] : ai0[2]; int s0 = bi2 ? t1 : t0;
          int u0 = bi1 ? ai1[1] : ai1[0]; int u1 = bi1 ? ai1[3] : ai1[2]; int s1 = bi2 ? u1 : u0;
          avi_ = brt ? s1 : s0; }
        float pi = fmaf((float)avi_, dscl[1], tb[1]);
        float Ei = fexp2(pi);
        float m1 = (1.f + Eg) * (1.f + Ei);

        af0 = MFMA_I8(wa[0][2][3], hf3, af0);
        af1 = MFMA_I8(wa[1][2][3], hf3, af1);
        int avf_;
        { int t0 = bi1 ? af0[1] : af0[0]; int t1 = bi1 ? af0[3] : af0[2]; int s0 = bi2 ? t1 : t0;
          int u0 = bi1 ? af1[1] : af1[0]; int u1 = bi1 ? af1[3] : af1[2]; int s1 = bi2 ? u1 : u0;
          avf_ = brt ? s1 : s0; }
        float pf = fmaf((float)avf_, dscl[2], tb[2]);
        float Ef = fexp2(pf);
        float fp1 = 1.f + Ef;
        float num = fmaf(cs, m1, (1.f - Eg) * fp1);
        float c   = num * frcp(m1 * fp1);
        cs = c;
        float Ec = fexp2(K_TANH * c);

        ao0 = MFMA_I8(wa[0][3][3], hf3, ao0);
        ao1 = MFMA_I8(wa[1][3][3], hf3, ao1);
        int avo_;
        { int t0 = bi1 ? ao0[1] : ao0[0]; int t1 = bi1 ? ao0[3] : ao0[2]; int s0 = bi2 ? t1 : t0;
          int u0 = bi1 ? ao1[1] : ao1[0]; int u1 = bi1 ? ao1[3] : ao1[2]; int s1 = bi2 ? u1 : u0;
          avo_ = brt ? s1 : s0; }
        float po = fmaf((float)avo_, dscl[3], tb[3]);
        float Eo = fexp2(po);
        float hh = (1.f - Ec) * frcp((1.f + Ec) * (1.f + Eo));
        hl = hh;
        *((char*)hbuf[1 - p] + hoff) = (char)((int)rintf(hh * 127.f));

        tb = tbn;
        __syncthreads();
    }

    hfin[col * 264 + row] = f2b(hl);
    __syncthreads();

    if (tid < 20) {
        int pc = tid / 10, cls = tid - pc * 10;
        const short* hcol = &hfin[pc * 264];
        const float* wrow = Wp + cls * 256;
        float sm = 0.f;
        #pragma unroll 8
        for (int k = 0; k < 256; k++) sm += b2f(hcol[k]) * wrow[k];
        out[(c0 + pc) * 10 + cls] = sm + bp[cls];
    }
}

extern "C" void kernel_launch(void* const* d_in, const int* in_sizes, int n_in,
                              void* d_out, int out_size, void* d_ws, size_t ws_size,
                              hipStream_t stream) {
    const int*   x   = (const int*)d_in[0];
    const float* emb = (const float*)d_in[1];
    const float* Wxg = (const float*)d_in[2];
    const float* Whg = (const float*)d_in[3];
    const float* bg  = (const float*)d_in[4];
    const float* Wxi = (const float*)d_in[5];
    const float* Whi = (const float*)d_in[6];
    const float* bi  = (const float*)d_in[7];
    const float* Wxf = (const float*)d_in[8];
    const float* Whf = (const float*)d_in[9];
    const float* bff = (const float*)d_in[10];
    const float* Wxo = (const float*)d_in[11];
    const float* Who = (const float*)d_in[12];
    const float* bo  = (const float*)d_in[13];
    const float* Wp  = (const float*)d_in[14];
    const float* bp  = (const float*)d_in[15];

    if (d_ws != nullptr && ws_size >= (size_t)WS_NEED) {
        hipMemsetAsync(d_ws, 0, WS_NEED, stream);   // kill stale flags (ABA across launches)
        hipLaunchKernelGGL(lstm_i8_split, dim3(256), dim3(512), 0, stream,
                           x, emb, Wxg, Whg, bg, Wxi, Whi, bi, Wxf, Whf, bff,
                           Wxo, Who, bo, Wp, bp, (char*)d_ws, (float*)d_out);
    } else {
        hipLaunchKernelGGL(lstm_i8_fb, dim3(128), dim3(512), 0, stream,
                           x, emb, Wxg, Whg, bg, Wxi, Whi, bi, Wxf, Whf, bff,
                           Wxo, Who, bo, Wp, bp, (float*)d_out);
    }
}

// Round 6
// 540.509 us; speedup vs baseline: 48.8723x; 48.8723x over previous
//
#include <hip/hip_runtime.h>
#include <hip/hip_bf16.h>

// LSTM B=256 T=512 H=256 E=6 V=10 C=10. fp32 in/out.
// ROUND 21: r18 (best verified, 510us steady) + STATIC WAVE-PRIORITY SKEW.
// r20's M-split: catastrophic (26ms) -> per-step cross-block sync through
// L2 + threadfence is ~100x too slow; recurrence must stay in-block, and
// the per-CU 256-MFMA/step floor (~1307cy) is un-splittable. r16/r19:
// intra-block flag sync pure overhead. Remaining lever: r18's ~1100cy
// exposed tail (elem-after-last-MFMA + barrier + read + ramp) is exposed
// for BOTH waves of a SIMD simultaneously because symmetric waves drain
// the shared matrix pipe in lockstep. elem has NO cross-wave dep (only
// write->barrier->read does), so waves may legally skew within a step.
// Fix: even waves run at s_setprio(1) for the whole loop -> their 32 MFMAs
// drain first (~650cy), their elem then overlaps the odd wave's MFMAs;
// only the odd wave's elem tail stays exposed. No flags, no spin, barrier
// semantics and math bit-identical (absmax must stay 0.0078125).
// Structure (r18): 128 blocks x 512 thr (8 waves, 2/SIMD), 2 cols/block,
// INT8 MFMA 16x16x64, reg-resident per-row-quantized weights
// (wa[2][4][4]=128 VGPR), h @127 double-buffered LDS, bias folded into
// per-col x-table tblC (80 KB LDS), tb(t+1) prefetch, Z C-operand,
// per-gate elem chunks after that gate's final MFMA, single-rcp c-update
// (5 exp2 + 2 rcp / elem), constant-index cndmask select.

typedef __attribute__((ext_vector_type(4))) int   int4v;
typedef __attribute__((ext_vector_type(4))) float float4v;

#define MFMA_I8(a, b, c) __builtin_amdgcn_mfma_i32_16x16x64_i8(a, b, c, 0, 0, 0)

#define K_TANH (-2.8853900817779268f)   // exp2(K_TANH*x) = e^(-2x)
#define K_SIG  (-1.4426950408889634f)   // exp2(K_SIG*x)  = e^(-x)

#define HSTRIDE 320                     // bytes per col in hbuf: 80 dw == 16 mod 32

__device__ __forceinline__ short f2b(float f) {
    __hip_bfloat16 b = __float2bfloat16(f); return *(short*)&b;
}
__device__ __forceinline__ float b2f(short s) {
    union { unsigned int u; float f; } v; v.u = ((unsigned int)(unsigned short)s) << 16; return v.f;
}
__device__ __forceinline__ float fexp2(float x) {
#if __has_builtin(__builtin_amdgcn_exp2f)
    return __builtin_amdgcn_exp2f(x);
#else
    return __expf(x * 0.6931471805599453f);
#endif
}
__device__ __forceinline__ float frcp(float x) { return __builtin_amdgcn_rcpf(x); }

__global__ __attribute__((amdgpu_flat_work_group_size(512, 512), amdgpu_waves_per_eu(2, 2)))
void lstm_i8(
    const int* __restrict__ x,
    const float* __restrict__ emb,
    const float* __restrict__ Wxg, const float* __restrict__ Whg, const float* __restrict__ bg,
    const float* __restrict__ Wxi, const float* __restrict__ Whi, const float* __restrict__ bi,
    const float* __restrict__ Wxf, const float* __restrict__ Whf, const float* __restrict__ bff,
    const float* __restrict__ Wxo, const float* __restrict__ Who, const float* __restrict__ bo,
    const float* __restrict__ Wp, const float* __restrict__ bp,
    float* __restrict__ out)
{
    const int tid = threadIdx.x, bid = blockIdx.x;
    const int c0 = bid * 2;                 // 2 batch columns per block
    const int w = tid >> 6, lane = tid & 63;
    const int l = lane & 15, q = lane >> 4;
    const int col = lane & 1;               // this thread's column (B n-parity)
    const int rtb = (lane >> 1) & 1;        // row-tile select bit
    const int si  = (lane >> 2) & 3;        // acc reg index
    const int rwb = 32 * w;                 // this wave's 32-row base
    const int row = rwb + 16 * rtb + 4 * q + si;   // this thread's hidden row

    __shared__ __align__(16) unsigned int hbuf[2][2 * HSTRIDE / 4];  // h i8 [parity][col][k]
    __shared__ __align__(16) short hfin[2 * 264];                    // final h bf16 [col][k]
    __shared__ unsigned char xdig2[512 * 2];                         // [t][col]
    __shared__ __align__(16) float tblC[2 * 10 * 1024];              // [col][d][row][4g], bias folded
    __shared__ float scaleL[4 * 256];                                // per-gate per-row max|W|

    const float* WxT[4] = {Wxg, Wxi, Wxf, Wxo};
    const float* WhT[4] = {Whg, Whi, Whf, Who};
    const float* bT[4]  = {bg, bi, bff, bo};

    // ---- init: zero h buf0, stage digits ----
    if (tid < 2 * HSTRIDE / 4) hbuf[0][tid] = 0u;
    for (int i = tid; i < 1024; i += 512)
        xdig2[i] = (unsigned char)x[(c0 + (i & 1)) * 512 + (i >> 1)];

    // ---- x-path table per col, bias + gate-scale folded: tblC[c][d][r][g] ----
    // 5120 float4 entries = 2 cols x 10 digits x 256 rows (2560 per col)
    for (int i = tid; i < 5120; i += 512) {
        int cc  = i / 2560;                   // 0 or 1
        int rem = i - cc * 2560;              // [0,2560)
        int d = rem >> 8, r = rem & 255;      // d in [0,10), consecutive lanes -> consecutive r
        float4v v;
        #pragma unroll
        for (int g = 0; g < 4; g++) {
            float s = 0.f;
            #pragma unroll
            for (int e = 0; e < 6; e++) s += WxT[g][r * 6 + e] * emb[d * 6 + e];
            v[g] = (s + bT[g][c0 + cc]) * (g == 0 ? K_TANH : K_SIG);
        }
        *(float4v*)&tblC[cc * 10240 + d * 1024 + r * 4] = v;
    }

    // ---- weight quantization: per-row scale, i8 A-frags in registers ----
    // Per row-tile rt (rows rwb+16rt .. +15): A[m=l -> row rwb+16rt+l]
    // [k = 64kt+16q+j], 16 i8 per lane per kt. wa[rt][g][kt] = 128 VGPRs.
    int4v wa[2][4][4];
    #pragma unroll
    for (int rt = 0; rt < 2; rt++) {
        #pragma unroll
        for (int g = 0; g < 4; g++) {
            const float* Wr = WhT[g] + (rwb + rt * 16 + l) * 256 + q * 16;
            float mx = 0.f;
            #pragma unroll
            for (int kt = 0; kt < 4; kt++)
                #pragma unroll
                for (int c4 = 0; c4 < 4; c4++) {
                    float4v v = *(const float4v*)(Wr + kt * 64 + c4 * 4);
                    #pragma unroll
                    for (int j = 0; j < 4; j++) mx = fmaxf(mx, fabsf(v[j]));
                }
            mx = fmaxf(mx, __shfl_xor(mx, 16));
            mx = fmaxf(mx, __shfl_xor(mx, 32));
            mx = fmaxf(mx, 1e-20f);
            if (q == 0) scaleL[g * 256 + rwb + rt * 16 + l] = mx;
            float qs = 127.f / mx;
            #pragma unroll
            for (int kt = 0; kt < 4; kt++) {
                int4v f;
                #pragma unroll
                for (int dw = 0; dw < 4; dw++) {
                    float4v v = *(const float4v*)(Wr + kt * 64 + dw * 4);
                    int word = 0;
                    #pragma unroll
                    for (int byt = 0; byt < 4; byt++) {
                        int z = (int)rintf(v[byt] * qs);
                        word |= (z & 255) << (8 * byt);
                    }
                    f[dw] = word;
                }
                wa[rt][g][kt] = f;
            }
        }
    }

    __syncthreads();   // scaleL/tblC/xdig2/hbuf[0] visible

    // ---- static wave-priority skew: even waves drain MFMAs first so their
    //      elem overlaps odd waves' MFMAs (phases anti-align per SIMD) ----
    if ((w & 1) == 0) __builtin_amdgcn_s_setprio(1);

    // ---- loop-invariant: dequant scales (this thread's row) ----
    float dscl[4];
    #pragma unroll
    for (int g = 0; g < 4; g++) {
        float kk = (g == 0 ? K_TANH : K_SIG) * (1.f / 16129.f);   // 127^2
        dscl[g] = scaleL[g * 256 + row] * kk;
    }

    const bool bi1 = (si & 1) != 0;
    const bool bi2 = (si & 2) != 0;
    const bool brt = rtb != 0;
    const float* tprow = tblC + col * 10240 + row * 4;   // + d*1024 at runtime
    const int hoff = col * HSTRIDE + row;                // this thread's h byte

    const int4v Z = {0, 0, 0, 0};          // loop-invariant zero C-operand

    float cs = 0.f, hl = 0.f;

    // prefetch tb for t=0
    float4v tb;
    { int dg = xdig2[0 * 2 + col]; tb = *(const float4v*)(tprow + dg * 1024); }

    for (int t = 0; t < 512; t++) {
        const int p = t & 1;
        const char* hbase = (const char*)hbuf[p] + col * HSTRIDE + q * 16;

        int4v hf0 = *(const int4v*)(hbase + 0 * 64);
        int4v hf1 = *(const int4v*)(hbase + 1 * 64);
        int4v hf2 = *(const int4v*)(hbase + 2 * 64);
        int4v hf3 = *(const int4v*)(hbase + 3 * 64);

        // k0..k2 for all 8 chains (2 row-tiles x 4 gates), round-robin issue
        int4v ag0 = MFMA_I8(wa[0][0][0], hf0, Z);
        int4v ag1 = MFMA_I8(wa[1][0][0], hf0, Z);
        int4v ai0 = MFMA_I8(wa[0][1][0], hf0, Z);
        int4v ai1 = MFMA_I8(wa[1][1][0], hf0, Z);
        int4v af0 = MFMA_I8(wa[0][2][0], hf0, Z);
        int4v af1 = MFMA_I8(wa[1][2][0], hf0, Z);
        int4v ao0 = MFMA_I8(wa[0][3][0], hf0, Z);
        int4v ao1 = MFMA_I8(wa[1][3][0], hf0, Z);
        ag0 = MFMA_I8(wa[0][0][1], hf1, ag0);
        ag1 = MFMA_I8(wa[1][0][1], hf1, ag1);
        ai0 = MFMA_I8(wa[0][1][1], hf1, ai0);
        ai1 = MFMA_I8(wa[1][1][1], hf1, ai1);
        af0 = MFMA_I8(wa[0][2][1], hf1, af0);
        af1 = MFMA_I8(wa[1][2][1], hf1, af1);
        ao0 = MFMA_I8(wa[0][3][1], hf1, ao0);
        ao1 = MFMA_I8(wa[1][3][1], hf1, ao1);
        ag0 = MFMA_I8(wa[0][0][2], hf2, ag0);
        ag1 = MFMA_I8(wa[1][0][2], hf2, ag1);
        ai0 = MFMA_I8(wa[0][1][2], hf2, ai0);
        ai1 = MFMA_I8(wa[1][1][2], hf2, ai1);
        af0 = MFMA_I8(wa[0][2][2], hf2, af0);
        af1 = MFMA_I8(wa[1][2][2], hf2, af1);
        ao0 = MFMA_I8(wa[0][3][2], hf2, ao0);
        ao1 = MFMA_I8(wa[1][3][2], hf2, ao1);

        // prefetch tb for t+1 (independent of h; overlaps MFMA/elementwise)
        float4v tbn;
        { int dgn = xdig2[((t + 1) & 511) * 2 + col]; tbn = *(const float4v*)(tprow + dgn * 1024); }

        // per-gate: final k3 MFMA pair, then that gate's elementwise chunk
        ag0 = MFMA_I8(wa[0][0][3], hf3, ag0);
        ag1 = MFMA_I8(wa[1][0][3], hf3, ag1);
        int avg_;
        { int t0 = bi1 ? ag0[1] : ag0[0]; int t1 = bi1 ? ag0[3] : ag0[2]; int s0 = bi2 ? t1 : t0;
          int u0 = bi1 ? ag1[1] : ag1[0]; int u1 = bi1 ? ag1[3] : ag1[2]; int s1 = bi2 ? u1 : u0;
          avg_ = brt ? s1 : s0; }
        float pg = fmaf((float)avg_, dscl[0], tb[0]);
        float Eg = fexp2(pg);

        ai0 = MFMA_I8(wa[0][1][3], hf3, ai0);
        ai1 = MFMA_I8(wa[1][1][3], hf3, ai1);
        int avi_;
        { int t0 = bi1 ? ai0[1] : ai0[0]; int t1 = bi1 ? ai0[3] : ai0[2]; int s0 = bi2 ? t1 : t0;
          int u0 = bi1 ? ai1[1] : ai1[0]; int u1 = bi1 ? ai1[3] : ai1[2]; int s1 = bi2 ? u1 : u0;
          avi_ = brt ? s1 : s0; }
        float pi = fmaf((float)avi_, dscl[1], tb[1]);
        float Ei = fexp2(pi);
        float m1 = (1.f + Eg) * (1.f + Ei);

        af0 = MFMA_I8(wa[0][2][3], hf3, af0);
        af1 = MFMA_I8(wa[1][2][3], hf3, af1);
        int avf_;
        { int t0 = bi1 ? af0[1] : af0[0]; int t1 = bi1 ? af0[3] : af0[2]; int s0 = bi2 ? t1 : t0;
          int u0 = bi1 ? af1[1] : af1[0]; int u1 = bi1 ? af1[3] : af1[2]; int s1 = bi2 ? u1 : u0;
          avf_ = brt ? s1 : s0; }
        float pf = fmaf((float)avf_, dscl[2], tb[2]);
        float Ef = fexp2(pf);
        // c = [(1-Eg)(1+Ef) + cs(1+Eg)(1+Ei)] / [(1+Eg)(1+Ei)(1+Ef)]  (one rcp)
        float fp1 = 1.f + Ef;
        float num = fmaf(cs, m1, (1.f - Eg) * fp1);
        float c   = num * frcp(m1 * fp1);
        cs = c;
        float Ec = fexp2(K_TANH * c);

        ao0 = MFMA_I8(wa[0][3][3], hf3, ao0);
        ao1 = MFMA_I8(wa[1][3][3], hf3, ao1);
        int avo_;
        { int t0 = bi1 ? ao0[1] : ao0[0]; int t1 = bi1 ? ao0[3] : ao0[2]; int s0 = bi2 ? t1 : t0;
          int u0 = bi1 ? ao1[1] : ao1[0]; int u1 = bi1 ? ao1[3] : ao1[2]; int s1 = bi2 ? u1 : u0;
          avo_ = brt ? s1 : s0; }
        float po = fmaf((float)avo_, dscl[3], tb[3]);
        float Eo = fexp2(po);
        float hh = (1.f - Ec) * frcp((1.f + Ec) * (1.f + Eo));   // tanh(c)*sig(o)
        hl = hh;
        *((char*)hbuf[1 - p] + hoff) = (char)((int)rintf(hh * 127.f));

        tb = tbn;
        __syncthreads();   // h_t (other buffer) fully written; h_{t-1} reads all done
    }

    if ((w & 1) == 0) __builtin_amdgcn_s_setprio(0);

    // ---- stage final h (exact f32->bf16) for projection ----
    hfin[col * 264 + row] = f2b(hl);
    __syncthreads();

    // ---- projection: out[c0+col][cls] = Wp[cls] . h_final + bp[cls] ----
    if (tid < 20) {
        int pc = tid / 10, cls = tid - pc * 10;
        const short* hcol = &hfin[pc * 264];
        const float* wrow = Wp + cls * 256;
        float s = 0.f;
        #pragma unroll 8
        for (int k = 0; k < 256; k++) s += b2f(hcol[k]) * wrow[k];
        out[(c0 + pc) * 10 + cls] = s + bp[cls];
    }
}

extern "C" void kernel_launch(void* const* d_in, const int* in_sizes, int n_in,
                              void* d_out, int out_size, void* d_ws, size_t ws_size,
                              hipStream_t stream) {
    const int*   x   = (const int*)d_in[0];
    const float* emb = (const float*)d_in[1];
    const float* Wxg = (const float*)d_in[2];
    const float* Whg = (const float*)d_in[3];
    const float* bg  = (const float*)d_in[4];
    const float* Wxi = (const float*)d_in[5];
    const float* Whi = (const float*)d_in[6];
    const float* bi  = (const float*)d_in[7];
    const float* Wxf = (const float*)d_in[8];
    const float* Whf = (const float*)d_in[9];
    const float* bff = (const float*)d_in[10];
    const float* Wxo = (const float*)d_in[11];
    const float* Who = (const float*)d_in[12];
    const float* bo  = (const float*)d_in[13];
    const float* Wp  = (const float*)d_in[14];
    const float* bp  = (const float*)d_in[15];

    hipLaunchKernelGGL(lstm_i8, dim3(128), dim3(512), 0, stream,
                       x, emb, Wxg, Whg, bg, Wxi, Whi, bi, Wxf, Whf, bff,
                       Wxo, Who, bo, Wp, bp, (float*)d_out);
}

// Round 7
// 523.196 us; speedup vs baseline: 50.4895x; 1.0331x over previous
//
#include <hip/hip_runtime.h>
#include <hip/hip_bf16.h>

// LSTM B=256 T=512 H=256 E=6 V=10 C=10. fp32 in/out.
// ROUND 22: r21 (495us, best) + pure loop-body trim, math bit-identical.
// Session conclusions so far: (1) sync-structure changes are exhausted --
// flags (r16,r19) and cross-block M-split (r20) regress, setprio skew (r21)
// gives +3%; (2) per-SIMD step budget: MFMA pipe ~1065-2300cy (MfmaUtil- vs
// ubench-implied i8 rate disagree 2x; if the ubench number is right we are
// already near MFMA-bound, explaining all failed overlap attempts);
// (3) the only guaranteed-positive lever left is removing instructions.
// This round:
//  - manual unroll x2: both parities' h read/write base addresses become
//    loop-invariant registers (no per-step parity selects / addr arith).
//  - digits stored as PRE-SCALED u16 offsets (dg<<12); ONE u32 LDS read per
//    2 steps replaces two u8 reads + shifts.
//  - everything else verbatim r21 (setprio skew, per-gate elem tails,
//    single-rcp c-update, constant-index cndmask select, tb prefetch).
// Structure: 128 blocks x 512 thr (8 waves, 2/SIMD), 2 cols/block, INT8
// MFMA 16x16x64, reg-resident per-row-quantized weights (wa[2][4][4]=128
// VGPR), h @127 double-buffered LDS, bias folded into per-col x-table tblC
// (80 KB LDS). absmax must stay exactly 0.0078125.
// PRE-COMMIT: if this lands >=490us, declare roofline (MFMA-pipe floor).

typedef __attribute__((ext_vector_type(4))) int   int4v;
typedef __attribute__((ext_vector_type(4))) float float4v;

#define MFMA_I8(a, b, c) __builtin_amdgcn_mfma_i32_16x16x64_i8(a, b, c, 0, 0, 0)

#define K_TANH (-2.8853900817779268f)   // exp2(K_TANH*x) = e^(-2x)
#define K_SIG  (-1.4426950408889634f)   // exp2(K_SIG*x)  = e^(-x)

#define HSTRIDE 320                     // bytes per col in hbuf: 80 dw == 16 mod 32

__device__ __forceinline__ short f2b(float f) {
    __hip_bfloat16 b = __float2bfloat16(f); return *(short*)&b;
}
__device__ __forceinline__ float b2f(short s) {
    union { unsigned int u; float f; } v; v.u = ((unsigned int)(unsigned short)s) << 16; return v.f;
}
__device__ __forceinline__ float fexp2(float x) {
#if __has_builtin(__builtin_amdgcn_exp2f)
    return __builtin_amdgcn_exp2f(x);
#else
    return __expf(x * 0.6931471805599453f);
#endif
}
__device__ __forceinline__ float frcp(float x) { return __builtin_amdgcn_rcpf(x); }

__global__ __attribute__((amdgpu_flat_work_group_size(512, 512), amdgpu_waves_per_eu(2, 2)))
void lstm_i8(
    const int* __restrict__ x,
    const float* __restrict__ emb,
    const float* __restrict__ Wxg, const float* __restrict__ Whg, const float* __restrict__ bg,
    const float* __restrict__ Wxi, const float* __restrict__ Whi, const float* __restrict__ bi,
    const float* __restrict__ Wxf, const float* __restrict__ Whf, const float* __restrict__ bff,
    const float* __restrict__ Wxo, const float* __restrict__ Who, const float* __restrict__ bo,
    const float* __restrict__ Wp, const float* __restrict__ bp,
    float* __restrict__ out)
{
    const int tid = threadIdx.x, bid = blockIdx.x;
    const int c0 = bid * 2;                 // 2 batch columns per block
    const int w = tid >> 6, lane = tid & 63;
    const int l = lane & 15, q = lane >> 4;
    const int col = lane & 1;               // this thread's column (B n-parity)
    const int rtb = (lane >> 1) & 1;        // row-tile select bit
    const int si  = (lane >> 2) & 3;        // acc reg index
    const int rwb = 32 * w;                 // this wave's 32-row base
    const int row = rwb + 16 * rtb + 4 * q + si;   // this thread's hidden row

    __shared__ __align__(16) unsigned int hbuf[2][2 * HSTRIDE / 4];  // h i8 [parity][col][k]
    __shared__ __align__(16) short hfin[2 * 264];                    // final h bf16 [col][k]
    __shared__ __align__(4) unsigned short xoff[2][512];             // [col][t] = digit<<12
    __shared__ __align__(16) float tblC[2 * 10 * 1024];              // [col][d][row][4g], bias folded
    __shared__ float scaleL[4 * 256];                                // per-gate per-row max|W|

    const float* WxT[4] = {Wxg, Wxi, Wxf, Wxo};
    const float* WhT[4] = {Whg, Whi, Whf, Who};
    const float* bT[4]  = {bg, bi, bff, bo};

    // ---- init: zero h buf0, stage pre-scaled digit offsets ----
    if (tid < 2 * HSTRIDE / 4) hbuf[0][tid] = 0u;
    for (int i = tid; i < 1024; i += 512) {
        int cc = i >> 9, t = i & 511;
        xoff[cc][t] = (unsigned short)(x[(c0 + cc) * 512 + t] << 12);
    }

    // ---- x-path table per col, bias + gate-scale folded: tblC[c][d][r][g] ----
    // 5120 float4 entries = 2 cols x 10 digits x 256 rows (2560 per col)
    for (int i = tid; i < 5120; i += 512) {
        int cc  = i / 2560;                   // 0 or 1
        int rem = i - cc * 2560;              // [0,2560)
        int d = rem >> 8, r = rem & 255;      // d in [0,10), consecutive lanes -> consecutive r
        float4v v;
        #pragma unroll
        for (int g = 0; g < 4; g++) {
            float s = 0.f;
            #pragma unroll
            for (int e = 0; e < 6; e++) s += WxT[g][r * 6 + e] * emb[d * 6 + e];
            v[g] = (s + bT[g][c0 + cc]) * (g == 0 ? K_TANH : K_SIG);
        }
        *(float4v*)&tblC[cc * 10240 + d * 1024 + r * 4] = v;
    }

    // ---- weight quantization: per-row scale, i8 A-frags in registers ----
    // Per row-tile rt (rows rwb+16rt .. +15): A[m=l -> row rwb+16rt+l]
    // [k = 64kt+16q+j], 16 i8 per lane per kt. wa[rt][g][kt] = 128 VGPRs.
    int4v wa[2][4][4];
    #pragma unroll
    for (int rt = 0; rt < 2; rt++) {
        #pragma unroll
        for (int g = 0; g < 4; g++) {
            const float* Wr = WhT[g] + (rwb + rt * 16 + l) * 256 + q * 16;
            float mx = 0.f;
            #pragma unroll
            for (int kt = 0; kt < 4; kt++)
                #pragma unroll
                for (int c4 = 0; c4 < 4; c4++) {
                    float4v v = *(const float4v*)(Wr + kt * 64 + c4 * 4);
                    #pragma unroll
                    for (int j = 0; j < 4; j++) mx = fmaxf(mx, fabsf(v[j]));
                }
            mx = fmaxf(mx, __shfl_xor(mx, 16));
            mx = fmaxf(mx, __shfl_xor(mx, 32));
            mx = fmaxf(mx, 1e-20f);
            if (q == 0) scaleL[g * 256 + rwb + rt * 16 + l] = mx;
            float qs = 127.f / mx;
            #pragma unroll
            for (int kt = 0; kt < 4; kt++) {
                int4v f;
                #pragma unroll
                for (int dw = 0; dw < 4; dw++) {
                    float4v v = *(const float4v*)(Wr + kt * 64 + dw * 4);
                    int word = 0;
                    #pragma unroll
                    for (int byt = 0; byt < 4; byt++) {
                        int z = (int)rintf(v[byt] * qs);
                        word |= (z & 255) << (8 * byt);
                    }
                    f[dw] = word;
                }
                wa[rt][g][kt] = f;
            }
        }
    }

    __syncthreads();   // scaleL/tblC/xoff/hbuf[0] visible

    // ---- static wave-priority skew (r21: +3%) ----
    if ((w & 1) == 0) __builtin_amdgcn_s_setprio(1);

    // ---- loop-invariant: dequant scales (this thread's row) ----
    float dscl[4];
    #pragma unroll
    for (int g = 0; g < 4; g++) {
        float kk = (g == 0 ? K_TANH : K_SIG) * (1.f / 16129.f);   // 127^2
        dscl[g] = scaleL[g * 256 + row] * kk;
    }

    const bool bi1 = (si & 1) != 0;
    const bool bi2 = (si & 2) != 0;
    const bool brt = rtb != 0;
    const char* tprowB = (const char*)(tblC + col * 10240 + row * 4);  // + off at runtime
    const int hoff = col * HSTRIDE + row;

    // loop-invariant h addresses (both parities)
    const char* hb0 = (const char*)hbuf[0] + col * HSTRIDE + q * 16;   // reads, parity 0
    const char* hb1 = (const char*)hbuf[1] + col * HSTRIDE + q * 16;   // reads, parity 1
    char* hw0 = (char*)hbuf[0] + hoff;                                 // write target of sub1
    char* hw1 = (char*)hbuf[1] + hoff;                                 // write target of sub0
    const char* xobase = (const char*)&xoff[col][0];                   // per-lane digit-offset base

    const int4v Z = {0, 0, 0, 0};          // loop-invariant zero C-operand

    float cs = 0.f, hl = 0.f;

    // prefetch: offsets for (t=0, t=1); tb for t=0
    unsigned int o01 = *(const unsigned int*)(xobase);
    float4v tbA = *(const float4v*)(tprowB + (o01 & 0xFFFFu));
    float4v tbB;

// One sub-step: reads HB, writes HW, consumes TBUSE, prefetches TBPRE = tb(OFFEXPR)
#define SUBSTEP(HB, HW, TBUSE, TBPRE, OFFEXPR)                                              \
    {                                                                                       \
        int4v hf0 = *(const int4v*)((HB) + 0 * 64);                                         \
        int4v hf1 = *(const int4v*)((HB) + 1 * 64);                                         \
        int4v hf2 = *(const int4v*)((HB) + 2 * 64);                                         \
        int4v hf3 = *(const int4v*)((HB) + 3 * 64);                                         \
        int4v ag0 = MFMA_I8(wa[0][0][0], hf0, Z);                                           \
        int4v ag1 = MFMA_I8(wa[1][0][0], hf0, Z);                                           \
        int4v ai0 = MFMA_I8(wa[0][1][0], hf0, Z);                                           \
        int4v ai1 = MFMA_I8(wa[1][1][0], hf0, Z);                                           \
        int4v af0 = MFMA_I8(wa[0][2][0], hf0, Z);                                           \
        int4v af1 = MFMA_I8(wa[1][2][0], hf0, Z);                                           \
        int4v ao0 = MFMA_I8(wa[0][3][0], hf0, Z);                                           \
        int4v ao1 = MFMA_I8(wa[1][3][0], hf0, Z);                                           \
        ag0 = MFMA_I8(wa[0][0][1], hf1, ag0);                                               \
        ag1 = MFMA_I8(wa[1][0][1], hf1, ag1);                                               \
        ai0 = MFMA_I8(wa[0][1][1], hf1, ai0);                                               \
        ai1 = MFMA_I8(wa[1][1][1], hf1, ai1);                                               \
        af0 = MFMA_I8(wa[0][2][1], hf1, af0);                                               \
        af1 = MFMA_I8(wa[1][2][1], hf1, af1);                                               \
        ao0 = MFMA_I8(wa[0][3][1], hf1, ao0);                                               \
        ao1 = MFMA_I8(wa[1][3][1], hf1, ao1);                                               \
        ag0 = MFMA_I8(wa[0][0][2], hf2, ag0);                                               \
        ag1 = MFMA_I8(wa[1][0][2], hf2, ag1);                                               \
        ai0 = MFMA_I8(wa[0][1][2], hf2, ai0);                                               \
        ai1 = MFMA_I8(wa[1][1][2], hf2, ai1);                                               \
        af0 = MFMA_I8(wa[0][2][2], hf2, af0);                                               \
        af1 = MFMA_I8(wa[1][2][2], hf2, af1);                                               \
        ao0 = MFMA_I8(wa[0][3][2], hf2, ao0);                                               \
        ao1 = MFMA_I8(wa[1][3][2], hf2, ao1);                                               \
        TBPRE = *(const float4v*)(tprowB + (OFFEXPR));                                      \
        ag0 = MFMA_I8(wa[0][0][3], hf3, ag0);                                               \
        ag1 = MFMA_I8(wa[1][0][3], hf3, ag1);                                               \
        int avg_;                                                                           \
        { int t0 = bi1 ? ag0[1] : ag0[0]; int t1 = bi1 ? ag0[3] : ag0[2]; int s0 = bi2 ? t1 : t0; \
          int u0 = bi1 ? ag1[1] : ag1[0]; int u1 = bi1 ? ag1[3] : ag1[2]; int s1 = bi2 ? u1 : u0; \
          avg_ = brt ? s1 : s0; }                                                           \
        float pg = fmaf((float)avg_, dscl[0], (TBUSE)[0]);                                  \
        float Eg = fexp2(pg);                                                               \
        ai0 = MFMA_I8(wa[0][1][3], hf3, ai0);                                               \
        ai1 = MFMA_I8(wa[1][1][3], hf3, ai1);                                               \
        int avi_;                                                                           \
        { int t0 = bi1 ? ai0[1] : ai0[0]; int t1 = bi1 ? ai0[3] : ai0[2]; int s0 = bi2 ? t1 : t0; \
          int u0 = bi1 ? ai1[1] : ai1[0]; int u1 = bi1 ? ai1[3] : ai1[2]; int s1 = bi2 ? u1 : u0; \
          avi_ = brt ? s1 : s0; }                                                           \
        float pi = fmaf((float)avi_, dscl[1], (TBUSE)[1]);                                  \
        float Ei = fexp2(pi);                                                               \
        float m1 = (1.f + Eg) * (1.f + Ei);                                                 \
        af0 = MFMA_I8(wa[0][2][3], hf3, af0);                                               \
        af1 = MFMA_I8(wa[1][2][3], hf3, af1);                                               \
        int avf_;                                                                           \
        { int t0 = bi1 ? af0[1] : af0[0]; int t1 = bi1 ? af0[3] : af0[2]; int s0 = bi2 ? t1 : t0; \
          int u0 = bi1 ? af1[1] : af1[0]; int u1 = bi1 ? af1[3] : af1[2]; int s1 = bi2 ? u1 : u0; \
          avf_ = brt ? s1 : s0; }                                                           \
        float pf = fmaf((float)avf_, dscl[2], (TBUSE)[2]);                                  \
        float Ef = fexp2(pf);                                                               \
        float fp1 = 1.f + Ef;                                                               \
        float num = fmaf(cs, m1, (1.f - Eg) * fp1);                                         \
        float c   = num * frcp(m1 * fp1);                                                   \
        cs = c;                                                                             \
        float Ec = fexp2(K_TANH * c);                                                       \
        ao0 = MFMA_I8(wa[0][3][3], hf3, ao0);                                               \
        ao1 = MFMA_I8(wa[1][3][3], hf3, ao1);                                               \
        int avo_;                                                                           \
        { int t0 = bi1 ? ao0[1] : ao0[0]; int t1 = bi1 ? ao0[3] : ao0[2]; int s0 = bi2 ? t1 : t0; \
          int u0 = bi1 ? ao1[1] : ao1[0]; int u1 = bi1 ? ao1[3] : ao1[2]; int s1 = bi2 ? u1 : u0; \
          avo_ = brt ? s1 : s0; }                                                           \
        float po = fmaf((float)avo_, dscl[3], (TBUSE)[3]);                                  \
        float Eo = fexp2(po);                                                               \
        float hh = (1.f - Ec) * frcp((1.f + Ec) * (1.f + Eo));                              \
        hl = hh;                                                                            \
        *(HW) = (char)((int)rintf(hh * 127.f));                                             \
        __syncthreads();                                                                    \
    }

    for (int i = 0; i < 256; ++i) {
        const int t2 = i << 1;
        int tnx = t2 + 2; if (tnx > 510) tnx = 510;     // uniform clamp (last iter dummy)
        unsigned int dn = *(const unsigned int*)(xobase + tnx * 2);   // offs (t+2, t+3)

        // sub-step t (even, parity 0): read hbuf0, write hbuf1, use tbA, prefetch tbB=tb(t+1)
        SUBSTEP(hb0, hw1, tbA, tbB, (o01 >> 16))
        // sub-step t+1 (odd, parity 1): read hbuf1, write hbuf0, use tbB, prefetch tbA=tb(t+2)
        SUBSTEP(hb1, hw0, tbB, tbA, (dn & 0xFFFFu))

        o01 = dn;
    }
#undef SUBSTEP

    if ((w & 1) == 0) __builtin_amdgcn_s_setprio(0);

    // ---- stage final h (exact f32->bf16) for projection ----
    hfin[col * 264 + row] = f2b(hl);
    __syncthreads();

    // ---- projection: out[c0+col][cls] = Wp[cls] . h_final + bp[cls] ----
    if (tid < 20) {
        int pc = tid / 10, cls = tid - pc * 10;
        const short* hcol = &hfin[pc * 264];
        const float* wrow = Wp + cls * 256;
        float s = 0.f;
        #pragma unroll 8
        for (int k = 0; k < 256; k++) s += b2f(hcol[k]) * wrow[k];
        out[(c0 + pc) * 10 + cls] = s + bp[cls];
    }
}

extern "C" void kernel_launch(void* const* d_in, const int* in_sizes, int n_in,
                              void* d_out, int out_size, void* d_ws, size_t ws_size,
                              hipStream_t stream) {
    const int*   x   = (const int*)d_in[0];
    const float* emb = (const float*)d_in[1];
    const float* Wxg = (const float*)d_in[2];
    const float* Whg = (const float*)d_in[3];
    const float* bg  = (const float*)d_in[4];
    const float* Wxi = (const float*)d_in[5];
    const float* Whi = (const float*)d_in[6];
    const float* bi  = (const float*)d_in[7];
    const float* Wxf = (const float*)d_in[8];
    const float* Whf = (const float*)d_in[9];
    const float* bff = (const float*)d_in[10];
    const float* Wxo = (const float*)d_in[11];
    const float* Who = (const float*)d_in[12];
    const float* bo  = (const float*)d_in[13];
    const float* Wp  = (const float*)d_in[14];
    const float* bp  = (const float*)d_in[15];

    hipLaunchKernelGGL(lstm_i8, dim3(128), dim3(512), 0, stream,
                       x, emb, Wxg, Whg, bg, Wxi, Whi, bi, Wxf, Whf, bff,
                       Wxo, Who, bo, Wp, bp, (float*)d_out);
}